// Round 5
// baseline (181.887 us; speedup 1.0000x reference)
//
#include <hip/hip_runtime.h>

#define BLOCK 256
#define VPT 2     // float4s per thread per row (straight-line, independent)
#define ROWS 4    // rows per block: shift-load latency amortized 4x, 16 loads in flight

typedef float f32x4 __attribute__((ext_vector_type(4)));

// out[b][j] = x[b][(j - s_b) mod T]
//
// Latency-bound fix v2: each block covers ROWS rows x VPT float4s/thread.
// The ROWS shift values are block-uniform scalar loads issued once up front
// (amortizing the serial shifts->x dependency 16x vs round 4). Phase 1 issues
// all 2*ROWS*VPT independent aligned vector loads back-to-back (deep MLP);
// phase 2 does block-uniform window-selects + non-temporal stores.
// All arrays are fully unrolled -> static indices (no scratch).

__device__ __forceinline__ f32x4 shuf(const f32x4 A, const f32x4 Bv, int a) {
    // window [a, a+3] of concat(A, Bv); a is block-uniform -> s_cbranch, no divergence
    f32x4 r;
    switch (a) {
        case 0:  r = A; break;
        case 1:  r.x = A.y; r.y = A.z; r.z = A.w; r.w = Bv.x; break;
        case 2:  r.x = A.z; r.y = A.w; r.z = Bv.x; r.w = Bv.y; break;
        default: r.x = A.w; r.y = Bv.x; r.z = Bv.y; r.w = Bv.z; break;
    }
    return r;
}

__global__ __launch_bounds__(BLOCK)
void roll_rows_mr(const float* __restrict__ x,
                  const int* __restrict__ shifts,
                  float* __restrict__ out,
                  int T, int T4, int B) {
    const int r0 = blockIdx.y * ROWS;
    const int v1 = blockIdx.x * (BLOCK * VPT) + (int)threadIdx.x;
    const int v2 = v1 + BLOCK;
    const int j1 = v1 << 2, j2 = v2 << 2;
    const bool p1 = v1 < T4, p2 = v2 < T4;

    // Phase 0: block-uniform shift loads (compile to s_load), issued together.
    int sa_[ROWS], a_[ROWS];
    bool ok_[ROWS];
#pragma unroll
    for (int r = 0; r < ROWS; ++r) {
        const int b = r0 + r;
        ok_[r] = (b < B);
        int s = ok_[r] ? (shifts[b] % T) : 0;   // shifts in [0,1000); defensive
        if (s < 0) s += T;
        const int a = (-s) & 3;                 // row-uniform misalignment
        int sa = s + a;                         // multiple of 4
        if (sa >= T) sa -= T;
        sa_[r] = sa; a_[r] = a;
    }

    // Phase 1: issue ALL independent aligned loads (16 per thread when full).
    f32x4 A1[ROWS], B1[ROWS], A2[ROWS], B2[ROWS];
#pragma unroll
    for (int r = 0; r < ROWS; ++r) {
        if (!ok_[r]) continue;
        const float* __restrict__ xr = x + (size_t)(r0 + r) * (size_t)T;
        if (p1) {
            int i = j1 - sa_[r]; if (i < 0) i += T;   // 16B-aligned, in [0, T-4]
            int ib = i + 4;      if (ib >= T) ib -= T;
            A1[r] = *reinterpret_cast<const f32x4*>(xr + i);
            B1[r] = *reinterpret_cast<const f32x4*>(xr + ib);  // next lane's A: L1 hit
        }
        if (p2) {
            int i = j2 - sa_[r]; if (i < 0) i += T;
            int ib = i + 4;      if (ib >= T) ib -= T;
            A2[r] = *reinterpret_cast<const f32x4*>(xr + i);
            B2[r] = *reinterpret_cast<const f32x4*>(xr + ib);
        }
    }

    // Phase 2: block-uniform selects + non-temporal stores.
#pragma unroll
    for (int r = 0; r < ROWS; ++r) {
        if (!ok_[r]) continue;
        float* __restrict__ outr = out + (size_t)(r0 + r) * (size_t)T;
        if (p1) __builtin_nontemporal_store(shuf(A1[r], B1[r], a_[r]),
                                            reinterpret_cast<f32x4*>(outr + j1));
        if (p2) __builtin_nontemporal_store(shuf(A2[r], B2[r], a_[r]),
                                            reinterpret_cast<f32x4*>(outr + j2));
    }
}

// Generic scalar fallback (T not divisible by 4).
__global__ void roll_rows_scalar(const float* __restrict__ x,
                                 const int* __restrict__ shifts,
                                 float* __restrict__ out,
                                 int T) {
    const int b = blockIdx.y;
    const int j = blockIdx.x * blockDim.x + threadIdx.x;
    if (j >= T) return;
    int s = shifts[b] % T;
    if (s < 0) s += T;
    int i = j - s;
    if (i < 0) i += T;
    out[(size_t)b * T + j] = x[(size_t)b * T + i];
}

extern "C" void kernel_launch(void* const* d_in, const int* in_sizes, int n_in,
                              void* d_out, int out_size, void* d_ws, size_t ws_size,
                              hipStream_t stream) {
    const float* x = (const float*)d_in[0];
    const int* shifts = (const int*)d_in[1];
    float* out = (float*)d_out;

    const int B = in_sizes[1];
    const int T = in_sizes[0] / B;

    if ((T & 3) == 0) {
        const int T4 = T / 4;
        dim3 block(BLOCK);
        dim3 grid((T4 + BLOCK * VPT - 1) / (BLOCK * VPT), (B + ROWS - 1) / ROWS);
        roll_rows_mr<<<grid, block, 0, stream>>>(x, shifts, out, T, T4, B);
    } else {
        dim3 block(256);
        dim3 grid((T + 255) / 256, B);
        roll_rows_scalar<<<grid, block, 0, stream>>>(x, shifts, out, T);
    }
}